// Round 1
// baseline (594.900 us; speedup 1.0000x reference)
//
#include <hip/hip_runtime.h>
#include <stdint.h>

#define B_ 8
#define C_ 256
#define N_ 4096
#define CQK 32
#define NT_ 64    // j (key) tile
#define MT_ 128   // i (query) rows per block

typedef __attribute__((ext_vector_type(8))) short bf16x8;
typedef __attribute__((ext_vector_type(4))) float f32x4;

__device__ __forceinline__ unsigned short f2bf_rne(float f) {
  unsigned u = __builtin_bit_cast(unsigned, f);
  u += 0x7FFFu + ((u >> 16) & 1u);
  return (unsigned short)(u >> 16);
}
__device__ __forceinline__ float bf2f(unsigned short h) {
  unsigned u = ((unsigned)h) << 16;
  return __builtin_bit_cast(float, u);
}

// ---------------------------------------------------------------------------
// Kernel 1: QKV projections. q,k in fp32 then split hi/lo bf16 (B,N,32);
// v as bf16 (B,C,N). One block = (batch b, 64-pixel tile). 256 thr.
// ---------------------------------------------------------------------------
__global__ __launch_bounds__(256) void proj_kernel(
    const float* __restrict__ x,
    const float* __restrict__ wq, const float* __restrict__ bq,
    const float* __restrict__ wk, const float* __restrict__ bk,
    const float* __restrict__ wv, const float* __restrict__ bv,
    unsigned short* __restrict__ qhi, unsigned short* __restrict__ qlo,
    unsigned short* __restrict__ khi, unsigned short* __restrict__ klo,
    unsigned short* __restrict__ vbf)
{
  __shared__ float xs[128 * 68];   // half of channels, [c][n] rows stride 68
  const int t    = threadIdx.x;
  const int nt   = blockIdx.x & 63;
  const int b    = blockIdx.x >> 6;
  const int lane = t & 63;
  const int wvid = __builtin_amdgcn_readfirstlane(t >> 6);

  // 320 output rows (32 q, 32 k, 256 v) in 40 groups of 8; wave takes g = wvid + 4*gi
  const float* wp[10]; const float* bp[10]; int kind[10]; int oo[10];
  #pragma unroll
  for (int gi = 0; gi < 10; ++gi) {
    int o0 = (wvid + 4 * gi) * 8;
    if (o0 < 32)      { wp[gi] = wq + o0 * 256;        bp[gi] = bq + o0;        kind[gi] = 0; oo[gi] = o0; }
    else if (o0 < 64) { wp[gi] = wk + (o0 - 32) * 256; bp[gi] = bk + (o0 - 32); kind[gi] = 1; oo[gi] = o0 - 32; }
    else              { wp[gi] = wv + (o0 - 64) * 256; bp[gi] = bv + (o0 - 64); kind[gi] = 2; oo[gi] = o0 - 64; }
  }

  float acc[10][8];
  #pragma unroll
  for (int gi = 0; gi < 10; ++gi)
    #pragma unroll
    for (int r = 0; r < 8; ++r) acc[gi][r] = 0.f;

  for (int h = 0; h < 2; ++h) {
    __syncthreads();
    for (int rd = 0; rd < 8; ++rd) {
      int c  = rd * 16 + (t >> 4);
      int n4 = (t & 15) * 4;
      const float4 xv = *(const float4*)(x + ((size_t)(b * C_ + h * 128 + c)) * N_ + nt * 64 + n4);
      *(float4*)&xs[c * 68 + n4] = xv;
    }
    __syncthreads();
    for (int c4 = 0; c4 < 32; ++c4) {
      float x0 = xs[(c4 * 4 + 0) * 68 + lane];
      float x1 = xs[(c4 * 4 + 1) * 68 + lane];
      float x2 = xs[(c4 * 4 + 2) * 68 + lane];
      float x3 = xs[(c4 * 4 + 3) * 68 + lane];
      #pragma unroll
      for (int gi = 0; gi < 10; ++gi) {
        const float* wrow = wp[gi] + h * 128 + c4 * 4;
        #pragma unroll
        for (int r = 0; r < 8; ++r) {
          float4 w4 = *(const float4*)(wrow + r * 256);
          acc[gi][r] = fmaf(w4.x, x0, acc[gi][r]);
          acc[gi][r] = fmaf(w4.y, x1, acc[gi][r]);
          acc[gi][r] = fmaf(w4.z, x2, acc[gi][r]);
          acc[gi][r] = fmaf(w4.w, x3, acc[gi][r]);
        }
      }
    }
  }

  const int n = nt * 64 + lane;
  #pragma unroll
  for (int gi = 0; gi < 10; ++gi) {
    #pragma unroll
    for (int r = 0; r < 8; ++r) {
      float v = acc[gi][r] + bp[gi][r];
      if (kind[gi] == 2) {
        vbf[((size_t)(b * C_ + oo[gi] + r)) * N_ + n] = f2bf_rne(v);
      } else {
        unsigned short hi = f2bf_rne(v);
        float rem = v - bf2f(hi);
        unsigned short lo = f2bf_rne(rem);
        size_t base = ((size_t)(b * N_ + n)) * CQK + oo[gi] + r;
        if (kind[gi] == 0) { qhi[base] = hi; qlo[base] = lo; }
        else               { khi[base] = hi; klo[base] = lo; }
      }
    }
  }
}

// ---------------------------------------------------------------------------
// Kernel 2: fused flash attention + residual. Writes y = gamma*attn + x to yout.
// Block: 512 thr (8 waves), M=128 queries, Nk=64 key tile. Grid 256 (1/CU),
// batch = blockIdx&7 (XCD-local K/V).
// ---------------------------------------------------------------------------
__global__ __launch_bounds__(512, 2) void attn_kernel(
    const float* __restrict__ x, const float* __restrict__ gptr,
    const unsigned short* __restrict__ qhi, const unsigned short* __restrict__ qlo,
    const unsigned short* __restrict__ khi, const unsigned short* __restrict__ klo,
    const unsigned short* __restrict__ vbf,
    float* __restrict__ yout)
{
  // LDS: K(hi|lo) 8192 | V 256*144=36864 | P 128*144=18432 | alpha 512 | l 512 | flags 8
  __shared__ __align__(16) char smem[64528];
  unsigned short* Vlds = (unsigned short*)(smem + 8192);
  unsigned short* Plds = (unsigned short*)(smem + 45056);
  float* alphal = (float*)(smem + 63488);
  float* lrowl  = (float*)(smem + 64000);
  int*   flagl  = (int*)(smem + 64512);

  const int t    = threadIdx.x;
  const int lane = t & 63;
  const int w    = __builtin_amdgcn_readfirstlane(t >> 6);
  const int b    = blockIdx.x & 7;
  const int it   = blockIdx.x >> 3;
  const int i0   = it * MT_;
  const int l15  = lane & 15;
  const int q4   = lane >> 4;
  const float gamma = gptr[0];

  // Q fragments (B-operand): lane -> n=i (l15), k=c' (q4*8+j). Stay in regs.
  const int iq = i0 + w * 16 + l15;
  const size_t qoff = ((size_t)(b * N_ + iq)) * CQK + q4 * 8;
  const bf16x8 qh = *(const bf16x8*)(qhi + qoff);
  const bf16x8 ql = *(const bf16x8*)(qlo + qoff);

  // PV mapping: wave = (c-strip of 64) x (i-half of 64)
  const int cstrip = w >> 1;
  const int ihalf  = w & 1;

  f32x4 acc[4][4];   // [cb][ib]
  const f32x4 zf = {0.f, 0.f, 0.f, 0.f};
  #pragma unroll
  for (int a1 = 0; a1 < 4; ++a1)
    #pragma unroll
    for (int a2 = 0; a2 < 4; ++a2) acc[a1][a2] = zf;

  float mold = -1e30f, lrun = 0.f;

  // staging: 5 x 16B per thread covers K(8KB) + V(32KB)
  uint4 stg[5];
  const int st_c   = w * 8 + (lane >> 3);       // V row (add r*64)
  const int st_jo  = (lane & 7) * 8;            // V j offset (elems)
  const int st_kj  = (w & 3) * 16 + (lane >> 2);
  const int st_kco = (lane & 3) * 8;
  const unsigned short* kbase = (w < 4) ? khi : klo;
  const int kldsoff = (w < 4) ? 0 : 4096;

  auto load_tile = [&](int j0) {
    #pragma unroll
    for (int r = 0; r < 4; ++r)
      stg[r] = *(const uint4*)(vbf + ((size_t)(b * C_ + r * 64 + st_c)) * N_ + j0 + st_jo);
    stg[4] = *(const uint4*)(kbase + ((size_t)(b * N_ + j0 + st_kj)) * CQK + st_kco);
  };
  auto write_tile = [&]() {
    #pragma unroll
    for (int r = 0; r < 4; ++r)
      *(uint4*)(((char*)Vlds) + (r * 64 + st_c) * 144 + st_jo * 2) = stg[r];
    *(uint4*)(smem + kldsoff + st_kj * 64 + st_kco * 2) = stg[4];
  };

  load_tile(0);
  write_tile();
  if (t == 0) { flagl[0] = 0; flagl[1] = 0; }
  __syncthreads();

  for (int jt = 0; jt < N_ / NT_; ++jt) {
    if (jt < N_ / NT_ - 1) load_tile((jt + 1) * NT_);

    // ---- S phase: S'[j][i] = K_t x Q, hi/lo compensated ----
    f32x4 sv[4];
    #pragma unroll
    for (int jb = 0; jb < 4; ++jb) {
      const char* ka = smem + (jb * 16 + l15) * 64 + q4 * 16;
      bf16x8 kh = *(const bf16x8*)ka;
      bf16x8 kl = *(const bf16x8*)(ka + 4096);
      f32x4 s = zf;
      s = __builtin_amdgcn_mfma_f32_16x16x32_bf16(kl, qh, s, 0, 0, 0);
      s = __builtin_amdgcn_mfma_f32_16x16x32_bf16(kh, ql, s, 0, 0, 0);
      s = __builtin_amdgcn_mfma_f32_16x16x32_bf16(kh, qh, s, 0, 0, 0);
      sv[jb] = s;
    }
    // online softmax; every per-lane value shares attention row i = l15
    float tmax = sv[0][0];
    #pragma unroll
    for (int jb = 0; jb < 4; ++jb)
      #pragma unroll
      for (int r = 0; r < 4; ++r) tmax = fmaxf(tmax, sv[jb][r]);
    tmax = fmaxf(tmax, __shfl_xor(tmax, 16));
    tmax = fmaxf(tmax, __shfl_xor(tmax, 32));
    float mnew = fmaxf(mold, tmax);
    bool upd = (mnew > mold);
    float alpha = __expf(mold - mnew);
    float tsum = 0.f;
    float pv[4][4];
    #pragma unroll
    for (int jb = 0; jb < 4; ++jb)
      #pragma unroll
      for (int r = 0; r < 4; ++r) {
        float p = __expf(sv[jb][r] - mnew);
        pv[jb][r] = p; tsum += p;
      }
    tsum += __shfl_xor(tsum, 16);
    tsum += __shfl_xor(tsum, 32);
    lrun = lrun * alpha + tsum;
    mold = mnew;

    {
      const int prow = w * 16 + l15;
      char* pb = ((char*)Plds) + prow * 144 + q4 * 8;
      #pragma unroll
      for (int jb = 0; jb < 4; ++jb) {
        unsigned u0 = __builtin_bit_cast(unsigned, pv[jb][0]);
        unsigned u1 = __builtin_bit_cast(unsigned, pv[jb][1]);
        unsigned u2 = __builtin_bit_cast(unsigned, pv[jb][2]);
        unsigned u3 = __builtin_bit_cast(unsigned, pv[jb][3]);
        uint2 pk;
        pk.x = (u0 >> 16) | (u1 & 0xFFFF0000u);
        pk.y = (u2 >> 16) | (u3 & 0xFFFF0000u);
        *(uint2*)(pb + jb * 32) = pk;
      }
      if (lane < 16) alphal[w * 16 + lane] = alpha;
      if (__ballot(upd) != 0ull) { if (lane == 0) flagl[jt & 1] = 1; }
      if (t == 0) flagl[(jt + 1) & 1] = 0;
    }
    __syncthreads();

    // ---- PV phase: O'[c][i] += V x P' ----
    if (flagl[jt & 1]) {
      #pragma unroll
      for (int ib = 0; ib < 4; ++ib) {
        float av = alphal[ihalf * 64 + ib * 16 + l15];
        #pragma unroll
        for (int cb = 0; cb < 4; ++cb)
          #pragma unroll
          for (int r = 0; r < 4; ++r) acc[cb][ib][r] *= av;
      }
    }
    #pragma unroll
    for (int ks = 0; ks < 2; ++ks) {
      bf16x8 pf[4];
      #pragma unroll
      for (int ib = 0; ib < 4; ++ib)
        pf[ib] = *(const bf16x8*)(((char*)Plds) + (ihalf * 64 + ib * 16 + l15) * 144 + ks * 64 + q4 * 16);
      #pragma unroll
      for (int cb = 0; cb < 4; ++cb) {
        bf16x8 vf = *(const bf16x8*)(((char*)Vlds) + (cstrip * 64 + cb * 16 + l15) * 144 + ks * 64 + q4 * 16);
        #pragma unroll
        for (int ib = 0; ib < 4; ++ib)
          acc[cb][ib] = __builtin_amdgcn_mfma_f32_16x16x32_bf16(vf, pf[ib], acc[cb][ib], 0, 0, 0);
      }
    }
    __syncthreads();
    if (jt < N_ / NT_ - 1) write_tile();
    __syncthreads();
  }

  // epilogue: O /= l; y = gamma*O + x
  if (lane < 16) lrowl[w * 16 + lane] = lrun;
  __syncthreads();
  #pragma unroll
  for (int ib = 0; ib < 4; ++ib) {
    float linv = 1.0f / lrowl[ihalf * 64 + ib * 16 + l15];
    int i = i0 + ihalf * 64 + ib * 16 + l15;
    #pragma unroll
    for (int cb = 0; cb < 4; ++cb) {
      #pragma unroll
      for (int r = 0; r < 4; ++r) {
        int c = cstrip * 64 + cb * 16 + q4 * 4 + r;
        size_t off = ((size_t)(b * C_ + c)) * N_ + i;
        float o = acc[cb][ib][r] * linv;
        yout[off] = fmaf(gamma, o, x[off]);
      }
    }
  }
}

// ---------------------------------------------------------------------------
// Kernel 3: BN statistics, one block per channel.
// ---------------------------------------------------------------------------
__global__ __launch_bounds__(256) void bnstats_kernel(
    const float* __restrict__ y, float* __restrict__ meanw, float* __restrict__ rstdw)
{
  const int c = blockIdx.x;
  const int t = threadIdx.x;
  float s1 = 0.f, s2 = 0.f;
  for (int b = 0; b < B_; ++b) {
    const float* p = y + ((size_t)(b * C_ + c)) * N_;
    #pragma unroll
    for (int r = 0; r < 4; ++r) {
      float4 v = *(const float4*)(p + r * 1024 + t * 4);
      s1 += v.x + v.y + v.z + v.w;
      s2 += v.x * v.x + v.y * v.y + v.z * v.z + v.w * v.w;
    }
  }
  __shared__ float r1[256], r2[256];
  r1[t] = s1; r2[t] = s2;
  __syncthreads();
  for (int s = 128; s > 0; s >>= 1) {
    if (t < s) { r1[t] += r1[t + s]; r2[t] += r2[t + s]; }
    __syncthreads();
  }
  if (t == 0) {
    float mean = r1[0] * (1.0f / 32768.0f);
    float var  = r2[0] * (1.0f / 32768.0f) - mean * mean;
    meanw[c] = mean;
    rstdw[c] = rsqrtf(var + 1e-5f);
  }
}

// ---------------------------------------------------------------------------
// Kernel 4: BN normalize + ReLU, in-place on d_out.
// ---------------------------------------------------------------------------
__global__ __launch_bounds__(256) void bnapply_kernel(
    float* __restrict__ y, const float* __restrict__ meanw, const float* __restrict__ rstdw,
    const float* __restrict__ bnw, const float* __restrict__ bnb)
{
  const int total4 = (B_ * C_ * N_) / 4;
  int idx = blockIdx.x * 256 + threadIdx.x;
  for (; idx < total4; idx += gridDim.x * 256) {
    int el = idx * 4;
    int c = (el >> 12) & 255;
    float sc = bnw[c] * rstdw[c];
    float sh = fmaf(-meanw[c], sc, bnb[c]);
    float4 v = *(float4*)(y + el);
    v.x = fmaxf(fmaf(v.x, sc, sh), 0.f);
    v.y = fmaxf(fmaf(v.y, sc, sh), 0.f);
    v.z = fmaxf(fmaf(v.z, sc, sh), 0.f);
    v.w = fmaxf(fmaf(v.w, sc, sh), 0.f);
    *(float4*)(y + el) = v;
  }
}

extern "C" void kernel_launch(void* const* d_in, const int* in_sizes, int n_in,
                              void* d_out, int out_size, void* d_ws, size_t ws_size,
                              hipStream_t stream)
{
  const float* x   = (const float*)d_in[0];
  const float* wq  = (const float*)d_in[1];
  const float* bq  = (const float*)d_in[2];
  const float* wk  = (const float*)d_in[3];
  const float* bk  = (const float*)d_in[4];
  const float* wv  = (const float*)d_in[5];
  const float* bv  = (const float*)d_in[6];
  const float* gm  = (const float*)d_in[7];
  const float* bnw = (const float*)d_in[8];
  const float* bnb = (const float*)d_in[9];
  float* out = (float*)d_out;

  // ws layout (needs ~24 MB): qhi|qlo|khi|klo 2MB each, vbf 16MB, mean/rstd
  char* ws = (char*)d_ws;
  unsigned short* qhi = (unsigned short*)(ws + (0u << 20));
  unsigned short* qlo = (unsigned short*)(ws + (2u << 20));
  unsigned short* khi = (unsigned short*)(ws + (4u << 20));
  unsigned short* klo = (unsigned short*)(ws + (6u << 20));
  unsigned short* vbf = (unsigned short*)(ws + (8u << 20));
  float* meanw = (float*)(ws + (24u << 20));
  float* rstdw = (float*)(ws + (24u << 20) + 1024);

  hipLaunchKernelGGL(proj_kernel, dim3(512), dim3(256), 0, stream,
                     x, wq, bq, wk, bk, wv, bv, qhi, qlo, khi, klo, vbf);
  hipLaunchKernelGGL(attn_kernel, dim3(256), dim3(512), 0, stream,
                     x, gm, qhi, qlo, khi, klo, vbf, out);
  hipLaunchKernelGGL(bnstats_kernel, dim3(256), dim3(256), 0, stream,
                     out, meanw, rstdw);
  hipLaunchKernelGGL(bnapply_kernel, dim3(2048), dim3(256), 0, stream,
                     out, meanw, rstdw, bnw, bnb);
}

// Round 2
// 298.100 us; speedup vs baseline: 1.9956x; 1.9956x over previous
//
#include <hip/hip_runtime.h>
#include <stdint.h>

#define B_ 8
#define C_ 256
#define N_ 4096
#define CQK 32

typedef __attribute__((ext_vector_type(8))) _Float16 f16x8;
typedef __attribute__((ext_vector_type(4))) float f32x4;

__device__ __forceinline__ unsigned short f2bf_rne(float f) {
  unsigned u = __builtin_bit_cast(unsigned, f);
  u += 0x7FFFu + ((u >> 16) & 1u);
  return (unsigned short)(u >> 16);
}

// ---------------------------------------------------------------------------
// Kernel 1: transpose x [b][c][n] fp32 -> xT [b][n][c] fp16 (c contiguous).
// Tile: 64 c x 128 n per block. 1024 blocks, 256 thr.
// ---------------------------------------------------------------------------
__global__ __launch_bounds__(256) void xpose_kernel(
    const float* __restrict__ x, _Float16* __restrict__ xT)
{
  __shared__ float xs[64 * 129];
  const int t  = threadIdx.x;
  const int blk = blockIdx.x;
  const int nt = blk & 31;          // n-tile (128 px)
  const int ct = (blk >> 5) & 3;    // c-tile (64 ch)
  const int b  = blk >> 7;
  const int c0 = ct * 64, n0 = nt * 128;

  #pragma unroll
  for (int p = 0; p < 8; ++p) {
    int cc = p * 8 + (t >> 5);
    int nn = (t & 31) * 4;
    float4 v = *(const float4*)(x + ((size_t)(b * C_ + c0 + cc)) * N_ + n0 + nn);
    xs[cc * 129 + nn]     = v.x;
    xs[cc * 129 + nn + 1] = v.y;
    xs[cc * 129 + nn + 2] = v.z;
    xs[cc * 129 + nn + 3] = v.w;
  }
  __syncthreads();
  #pragma unroll
  for (int p = 0; p < 4; ++p) {
    int id = p * 256 + t;
    int cchunk = id & 7, n = id >> 3;   // n in [0,128)
    _Float16 h[8];
    #pragma unroll
    for (int j = 0; j < 8; ++j) h[j] = (_Float16)xs[(cchunk * 8 + j) * 129 + n];
    *(f16x8*)(xT + ((size_t)(b * N_) + n0 + n) * C_ + c0 + cchunk * 8) = *(f16x8*)h;
  }
}

// ---------------------------------------------------------------------------
// Kernel 2: convert weights to fp16, concatenated Wcat[320][256]:
// rows 0-31 = wq, 32-63 = wk, 64-319 = wv.
// ---------------------------------------------------------------------------
__global__ __launch_bounds__(256) void wconv_kernel(
    const float* __restrict__ wq, const float* __restrict__ wk,
    const float* __restrict__ wv, _Float16* __restrict__ wf)
{
  int idx = blockIdx.x * 256 + threadIdx.x;   // 20480 threads x 4 elems
  int e = idx * 4;
  int o = e >> 8, c = e & 255;
  const float* src;
  if (o < 32)      src = wq + o * 256 + c;
  else if (o < 64) src = wk + (o - 32) * 256 + c;
  else             src = wv + (o - 64) * 256 + c;
  float4 v = *(const float4*)src;
  _Float16 h[4] = {(_Float16)v.x, (_Float16)v.y, (_Float16)v.z, (_Float16)v.w};
  *(uint2*)(wf + e) = *(uint2*)h;
}

// ---------------------------------------------------------------------------
// Kernel 3: projection GEMM (fp16 MFMA): D[o][n] = Wcat[o][:] . xT[n][:]
// Block = 64 o x 128 n, 256 thr (4 waves: wave = 32 o x 64 n).
// otile 0 -> q/k rows (store transposed [n][c']); otiles 1-4 -> v [c][n].
// No LDS, operands straight from L2.
// ---------------------------------------------------------------------------
__global__ __launch_bounds__(256, 4) void proj_gemm_kernel(
    const _Float16* __restrict__ xT, const _Float16* __restrict__ wf,
    const float* __restrict__ bq, const float* __restrict__ bk,
    const float* __restrict__ bv,
    _Float16* __restrict__ qf, _Float16* __restrict__ kf,
    _Float16* __restrict__ vout)
{
  const int t = threadIdx.x, lane = t & 63;
  const int w = t >> 6;
  const int l15 = lane & 15, q4 = lane >> 4;
  const int blk = blockIdx.x;
  const int otile = blk % 5;          // 0 = q/k, 1..4 = v
  const int nt = blk / 5;             // 256 n-tiles (8 b x 32)
  const int b  = nt >> 5;
  const int n0 = (nt & 31) * 128;
  const int o0w = (w & 1) * 32;       // wave o-offset within the 64-row tile
  const int n0w = (w >> 1) * 64;      // wave n-offset within the 128-px tile

  f32x4 acc[2][4];
  const f32x4 zf = {0.f, 0.f, 0.f, 0.f};
  #pragma unroll
  for (int a = 0; a < 2; ++a)
    #pragma unroll
    for (int bb = 0; bb < 4; ++bb) acc[a][bb] = zf;

  const _Float16* wbase = wf + (size_t)(otile * 64 + o0w) * 256;
  const _Float16* xbase = xT + ((size_t)(b * N_) + n0 + n0w) * C_;

  #pragma unroll
  for (int kc = 0; kc < 8; ++kc) {
    f16x8 af[2], bfr[4];
    #pragma unroll
    for (int ob = 0; ob < 2; ++ob)
      af[ob] = *(const f16x8*)(wbase + (ob * 16 + l15) * 256 + kc * 32 + q4 * 8);
    #pragma unroll
    for (int nb = 0; nb < 4; ++nb)
      bfr[nb] = *(const f16x8*)(xbase + (nb * 16 + l15) * 256 + kc * 32 + q4 * 8);
    #pragma unroll
    for (int ob = 0; ob < 2; ++ob)
      #pragma unroll
      for (int nb = 0; nb < 4; ++nb)
        acc[ob][nb] = __builtin_amdgcn_mfma_f32_16x16x32_f16(af[ob], bfr[nb], acc[ob][nb], 0, 0, 0);
  }

  if (otile == 0) {
    _Float16* dst = (o0w == 0) ? qf : kf;
    const float* bias = (o0w == 0) ? bq : bk;
    #pragma unroll
    for (int ob = 0; ob < 2; ++ob) {
      float4 b4 = *(const float4*)(bias + ob * 16 + q4 * 4);
      #pragma unroll
      for (int nb = 0; nb < 4; ++nb) {
        int pixel = n0 + n0w + nb * 16 + l15;
        _Float16 h[4];
        h[0] = (_Float16)(acc[ob][nb][0] + b4.x);
        h[1] = (_Float16)(acc[ob][nb][1] + b4.y);
        h[2] = (_Float16)(acc[ob][nb][2] + b4.z);
        h[3] = (_Float16)(acc[ob][nb][3] + b4.w);
        *(uint2*)(dst + ((size_t)(b * N_) + pixel) * CQK + ob * 16 + q4 * 4) = *(uint2*)h;
      }
    }
  } else {
    int cbase = (otile - 1) * 64 + o0w;
    #pragma unroll
    for (int ob = 0; ob < 2; ++ob) {
      float4 b4 = *(const float4*)(bv + cbase + ob * 16 + q4 * 4);
      #pragma unroll
      for (int nb = 0; nb < 4; ++nb) {
        int pixel = n0 + n0w + nb * 16 + l15;
        #pragma unroll
        for (int r = 0; r < 4; ++r) {
          int c = cbase + ob * 16 + q4 * 4 + r;
          float bval = (r == 0) ? b4.x : (r == 1) ? b4.y : (r == 2) ? b4.z : b4.w;
          vout[((size_t)(b * C_) + c) * N_ + pixel] = (_Float16)(acc[ob][nb][r] + bval);
        }
      }
    }
  }
}

// ---------------------------------------------------------------------------
// Kernel 4: fused flash attention + residual -> yout (bf16).
// 512 thr (8 waves), M=64 queries/block, NT=64 keys/iter, grid 512 (2/CU).
// S-phase: wave = (qgroup of 16 q) x (j-half of 32). PV: wave = c-strip of 32.
// K/V read directly from global (L2); only P round-trips LDS. 2 barriers/iter.
// ---------------------------------------------------------------------------
__global__ __launch_bounds__(512, 4) void attn_kernel(
    const float* __restrict__ x, const float* __restrict__ gptr,
    const _Float16* __restrict__ qf, const _Float16* __restrict__ kf,
    const _Float16* __restrict__ vf, unsigned short* __restrict__ yout)
{
  __shared__ __align__(16) char smem[10768];
  _Float16* Plds  = (_Float16*)smem;            // 64 rows (i), stride 144 B
  float* pmax   = (float*)(smem + 9216);        // [2][64]
  float* psum   = (float*)(smem + 9728);        // [2][64]
  float* alphal = (float*)(smem + 10240);       // [64]
  float* lrowl  = (float*)(smem + 10496);       // [64]
  int*   flagl  = (int*)(smem + 10752);         // [2]

  const int t = threadIdx.x, lane = t & 63;
  const int w = t >> 6;
  const int l15 = lane & 15, q4 = lane >> 4;
  const int b  = blockIdx.x & 7;
  const int it = blockIdx.x >> 3;
  const int i0 = it * 64;
  const int qg = w >> 1, jh = w & 1;
  const int row = qg * 16 + l15;
  const float gamma = gptr[0];

  const f16x8 qfr = *(const f16x8*)(qf + ((size_t)(b * N_) + i0 + qg * 16 + l15) * CQK + q4 * 8);

  f32x4 acc[2][4];   // [cb][ib]: c = w*32+cb*16+q4*4+r, i = ib*16+l15
  const f32x4 zf = {0.f, 0.f, 0.f, 0.f};
  #pragma unroll
  for (int a = 0; a < 2; ++a)
    #pragma unroll
    for (int bb = 0; bb < 4; ++bb) acc[a][bb] = zf;

  float mold = -1e30f, lrun = 0.f;

  for (int jt = 0; jt < N_ / 64; ++jt) {
    const int jbase = jt * 64;

    // issue K (this wave's j-half) and V (this wave's c-strip) loads
    f16x8 kfr[2];
    #pragma unroll
    for (int jbb = 0; jbb < 2; ++jbb) {
      int j = jbase + (jh * 2 + jbb) * 16 + l15;
      kfr[jbb] = *(const f16x8*)(kf + ((size_t)(b * N_) + j) * CQK + q4 * 8);
    }
    f16x8 vfr[2][2];
    #pragma unroll
    for (int ks = 0; ks < 2; ++ks)
      #pragma unroll
      for (int cb = 0; cb < 2; ++cb)
        vfr[ks][cb] = *(const f16x8*)(vf + ((size_t)(b * C_) + w * 32 + cb * 16 + l15) * N_ + jbase + ks * 32 + q4 * 8);

    // ---- S phase: S'[j][i] for this wave's 32 j x 16 i ----
    f32x4 sv[2];
    #pragma unroll
    for (int jbb = 0; jbb < 2; ++jbb)
      sv[jbb] = __builtin_amdgcn_mfma_f32_16x16x32_f16(kfr[jbb], qfr, zf, 0, 0, 0);

    float lm = fmaxf(fmaxf(fmaxf(sv[0][0], sv[0][1]), fmaxf(sv[0][2], sv[0][3])),
                     fmaxf(fmaxf(sv[1][0], sv[1][1]), fmaxf(sv[1][2], sv[1][3])));
    lm = fmaxf(lm, __shfl_xor(lm, 16));
    lm = fmaxf(lm, __shfl_xor(lm, 32));
    if (lane < 16) pmax[jh * 64 + qg * 16 + lane] = lm;
    __syncthreads();                                   // bar1

    float mnew = fmaxf(mold, fmaxf(pmax[row], pmax[64 + row]));
    bool upd = mnew > mold;
    float alpha = __expf(mold - mnew);
    float p[2][4];
    float ts = 0.f;
    #pragma unroll
    for (int jbb = 0; jbb < 2; ++jbb)
      #pragma unroll
      for (int r = 0; r < 4; ++r) {
        float pv = __expf(sv[jbb][r] - mnew);
        p[jbb][r] = pv; ts += pv;
      }
    ts += __shfl_xor(ts, 16);
    ts += __shfl_xor(ts, 32);
    if (lane < 16) psum[jh * 64 + qg * 16 + lane] = ts;
    if (jh == 0 && lane < 16) alphal[qg * 16 + lane] = alpha;
    {
      char* pb = (char*)Plds + (qg * 16 + l15) * 144 + jh * 64 + q4 * 8;
      #pragma unroll
      for (int jbb = 0; jbb < 2; ++jbb) {
        _Float16 h[4];
        h[0] = (_Float16)p[jbb][0];
        h[1] = (_Float16)p[jbb][1];
        h[2] = (_Float16)p[jbb][2];
        h[3] = (_Float16)p[jbb][3];
        *(uint2*)(pb + jbb * 32) = *(uint2*)h;
      }
    }
    if (__ballot(upd) != 0ull) { if (lane == 0) flagl[jt & 1] = 1; }
    if (t == 0) flagl[(jt + 1) & 1] = 0;
    mold = mnew;
    __syncthreads();                                   // bar2

    lrun = lrun * alpha + psum[row] + psum[64 + row];

    // ---- PV: O'[c][i] += V x P' ----
    if (flagl[jt & 1]) {
      #pragma unroll
      for (int ib = 0; ib < 4; ++ib) {
        float av = alphal[ib * 16 + l15];
        #pragma unroll
        for (int cb = 0; cb < 2; ++cb)
          #pragma unroll
          for (int r = 0; r < 4; ++r) acc[cb][ib][r] *= av;
      }
    }
    #pragma unroll
    for (int ks = 0; ks < 2; ++ks) {
      f16x8 pf[4];
      #pragma unroll
      for (int ib = 0; ib < 4; ++ib)
        pf[ib] = *(const f16x8*)((char*)Plds + (ib * 16 + l15) * 144 + ks * 64 + q4 * 16);
      #pragma unroll
      for (int cb = 0; cb < 2; ++cb)
        #pragma unroll
        for (int ib = 0; ib < 4; ++ib)
          acc[cb][ib] = __builtin_amdgcn_mfma_f32_16x16x32_f16(vfr[ks][cb], pf[ib], acc[cb][ib], 0, 0, 0);
    }
    // no barrier here: next iter's first LDS write (pmax) is fenced by bar1,
    // and P/alphal/psum writes happen after the next bar1.
  }

  if (jh == 0 && lane < 16) lrowl[qg * 16 + lane] = lrun;
  __syncthreads();
  #pragma unroll
  for (int ib = 0; ib < 4; ++ib) {
    float linv = 1.0f / lrowl[ib * 16 + l15];
    int i = i0 + ib * 16 + l15;
    #pragma unroll
    for (int cb = 0; cb < 2; ++cb) {
      #pragma unroll
      for (int r = 0; r < 4; ++r) {
        int c = w * 32 + cb * 16 + q4 * 4 + r;
        size_t off = ((size_t)(b * C_) + c) * N_ + i;
        float o = acc[cb][ib][r] * linv;
        yout[off] = f2bf_rne(fmaf(gamma, o, x[off]));
      }
    }
  }
}

// ---------------------------------------------------------------------------
// Kernel 5: BN statistics from bf16 yout; one block per channel.
// ---------------------------------------------------------------------------
__global__ __launch_bounds__(256) void bnstats_kernel(
    const unsigned short* __restrict__ y, float* __restrict__ meanw, float* __restrict__ rstdw)
{
  const int c = blockIdx.x;
  const int t = threadIdx.x;
  float s1 = 0.f, s2 = 0.f;
  for (int b = 0; b < B_; ++b) {
    const unsigned short* p = y + ((size_t)(b * C_ + c)) * N_;
    #pragma unroll
    for (int r = 0; r < 2; ++r) {
      uint4 u = *(const uint4*)(p + r * 2048 + t * 8);
      unsigned uu[4] = {u.x, u.y, u.z, u.w};
      #pragma unroll
      for (int k = 0; k < 4; ++k) {
        float a = __builtin_bit_cast(float, uu[k] << 16);
        float bb = __builtin_bit_cast(float, uu[k] & 0xFFFF0000u);
        s1 += a + bb;
        s2 += a * a + bb * bb;
      }
    }
  }
  __shared__ float r1[256], r2[256];
  r1[t] = s1; r2[t] = s2;
  __syncthreads();
  for (int s = 128; s > 0; s >>= 1) {
    if (t < s) { r1[t] += r1[t + s]; r2[t] += r2[t + s]; }
    __syncthreads();
  }
  if (t == 0) {
    float mean = r1[0] * (1.0f / 32768.0f);
    float var  = r2[0] * (1.0f / 32768.0f) - mean * mean;
    meanw[c] = mean;
    rstdw[c] = rsqrtf(var + 1e-5f);
  }
}

// ---------------------------------------------------------------------------
// Kernel 6: BN normalize + ReLU: bf16 yout -> fp32 d_out.
// ---------------------------------------------------------------------------
__global__ __launch_bounds__(256) void bnapply_kernel(
    const unsigned short* __restrict__ y, float* __restrict__ out,
    const float* __restrict__ meanw, const float* __restrict__ rstdw,
    const float* __restrict__ bnw, const float* __restrict__ bnb)
{
  size_t idx = (size_t)blockIdx.x * 256 + threadIdx.x;   // 1,048,576 threads
  size_t el = idx * 8;
  int c = (int)((el >> 12) & 255);
  float sc = bnw[c] * rstdw[c];
  float sh = fmaf(-meanw[c], sc, bnb[c]);
  uint4 u = *(const uint4*)(y + el);
  unsigned uu[4] = {u.x, u.y, u.z, u.w};
  float4 o0, o1;
  float v[8];
  #pragma unroll
  for (int k = 0; k < 4; ++k) {
    v[2 * k]     = __builtin_bit_cast(float, uu[k] << 16);
    v[2 * k + 1] = __builtin_bit_cast(float, uu[k] & 0xFFFF0000u);
  }
  o0.x = fmaxf(fmaf(v[0], sc, sh), 0.f);
  o0.y = fmaxf(fmaf(v[1], sc, sh), 0.f);
  o0.z = fmaxf(fmaf(v[2], sc, sh), 0.f);
  o0.w = fmaxf(fmaf(v[3], sc, sh), 0.f);
  o1.x = fmaxf(fmaf(v[4], sc, sh), 0.f);
  o1.y = fmaxf(fmaf(v[5], sc, sh), 0.f);
  o1.z = fmaxf(fmaf(v[6], sc, sh), 0.f);
  o1.w = fmaxf(fmaf(v[7], sc, sh), 0.f);
  *(float4*)(out + el) = o0;
  *(float4*)(out + el + 4) = o1;
}

extern "C" void kernel_launch(void* const* d_in, const int* in_sizes, int n_in,
                              void* d_out, int out_size, void* d_ws, size_t ws_size,
                              hipStream_t stream)
{
  const float* x   = (const float*)d_in[0];
  const float* wq  = (const float*)d_in[1];
  const float* bq  = (const float*)d_in[2];
  const float* wk  = (const float*)d_in[3];
  const float* bk  = (const float*)d_in[4];
  const float* wv  = (const float*)d_in[5];
  const float* bv  = (const float*)d_in[6];
  const float* gm  = (const float*)d_in[7];
  const float* bnw = (const float*)d_in[8];
  const float* bnb = (const float*)d_in[9];
  float* out = (float*)d_out;

  // d_out doubles as scratch for xT and v (both dead before bnapply writes):
  //   [0, 16.78 MB)   xT fp16 [b][n][c]
  //   [16.78, 33.55)  v  fp16 [b][c][n]
  _Float16* xT  = (_Float16*)d_out;
  _Float16* vfp = (_Float16*)((char*)d_out + (size_t)B_ * C_ * N_ * 2);

  // ws: q 2MB | k 2MB | yout bf16 16.78MB | wf 160KB | stats  (~22 MB total)
  char* ws = (char*)d_ws;
  _Float16* qf = (_Float16*)(ws);
  _Float16* kf = (_Float16*)(ws + ((size_t)2 << 20));
  unsigned short* yout = (unsigned short*)(ws + ((size_t)4 << 20));
  _Float16* wf = (_Float16*)(ws + ((size_t)21 << 20));
  float* meanw = (float*)(ws + ((size_t)22 << 20));
  float* rstdw = (float*)(ws + ((size_t)22 << 20) + 4096);

  hipLaunchKernelGGL(xpose_kernel, dim3(1024), dim3(256), 0, stream, x, xT);
  hipLaunchKernelGGL(wconv_kernel, dim3(80), dim3(256), 0, stream, wq, wk, wv, wf);
  hipLaunchKernelGGL(proj_gemm_kernel, dim3(1280), dim3(256), 0, stream,
                     xT, wf, bq, bk, bv, qf, kf, vfp);
  hipLaunchKernelGGL(attn_kernel, dim3(512), dim3(512), 0, stream,
                     x, gm, qf, kf, vfp, yout);
  hipLaunchKernelGGL(bnstats_kernel, dim3(256), dim3(256), 0, stream,
                     yout, meanw, rstdw);
  hipLaunchKernelGGL(bnapply_kernel, dim3(4096), dim3(256), 0, stream,
                     yout, out, meanw, rstdw, bnw, bnb);
}